// Round 4
// baseline (795.328 us; speedup 1.0000x reference)
//
#include <hip/hip_runtime.h>
#include <cstdint>
#include <math.h>

// Problem constants (from reference)
constexpr int B = 32;
constexpr int M = 5120;          // 32*32*5 anchors
constexpr int C = 80;            // classes
constexpr int K = 1000;          // TOPK
constexpr float NMS_T  = 0.6f;

// d_out layout (flat float32, return order): scores | labels | bboxes | keep
constexpr int OFF_SCORE = 0;
constexpr int OFF_LAB   = B * K;            // 32000
constexpr int OFF_BOX   = 2 * B * K;        // 64000
constexpr int OFF_KEEP  = 2 * B * K + 4 * B * K; // 192000

// workspace layout (bytes)
constexpr size_t WS_KEYS     = 0;                                   // B*M u64
constexpr size_t WS_LABELS   = WS_KEYS   + (size_t)B * M * 8;       // B*M int
constexpr size_t WS_SELIDX   = WS_LABELS + (size_t)B * M * 4;       // B*K int
constexpr size_t WS_SELSC    = WS_SELIDX + (size_t)B * K * 4;       // B*K f32
constexpr size_t WS_SELLAB   = WS_SELSC + (size_t)B * K * 4;        // B*K int
constexpr size_t WS_BOXOFF   = WS_SELLAB + (size_t)B * K * 4;       // B*K*4 f32
constexpr size_t WS_MASK     = WS_BOXOFF + (size_t)B * K * 4 * 4;   // B*K*16 u64
constexpr size_t WS_KEEP     = WS_MASK + (size_t)B * K * 16 * 8;    // B*16 u64

// Correctly-rounded f32 exp: compute in f64 (ocml exp, ~0.5 ulp f64), round
// once to f32. Matches glibc expf (np.exp on f32) except w.p. ~1e-9/call.
__device__ __forceinline__ float expf_cr(float x) {
    return (float)exp((double)x);
}
// numpy-style f32 sigmoid: 1/(1+exp(-x)), every op in f32, no contraction.
__device__ __forceinline__ float sigm_np(float x) {
    float e = expf_cr(-x);
    return __fdiv_rn(1.0f, __fadd_rn(1.0f, e));
}

// Kernel 1: replicate numpy-f32 score_all = sigmoid(conf)*softmax(cls);
// scores = max_c, labels = argmax_c (first max). Softmax denominator uses
// numpy's pairwise-sum order for n=80: 8 accumulators stride-8, tree combine.
__global__ void k_scores(const float* __restrict__ conf, const float* __restrict__ cls,
                         unsigned long long* __restrict__ keys, int* __restrict__ labels) {
    int m = blockIdx.x * blockDim.x + threadIdx.x;   // grid.x = 20, block 256
    int b = blockIdx.y;
    size_t t = (size_t)b * M + m;
    const float4* rowv = (const float4*)(cls + t * C);
    float ev[80];
#pragma unroll
    for (int i = 0; i < 20; i++) {
        float4 v = rowv[i];
        ev[4 * i + 0] = v.x; ev[4 * i + 1] = v.y;
        ev[4 * i + 2] = v.z; ev[4 * i + 3] = v.w;
    }
    // max (order-independent)
    float mx = ev[0];
#pragma unroll
    for (int c = 1; c < 80; c++) mx = fmaxf(mx, ev[c]);
    // e_c = exp(f32(x - mx)), correctly rounded
#pragma unroll
    for (int c = 0; c < 80; c++) ev[c] = expf_cr(__fsub_rn(ev[c], mx));
    // numpy pairwise sum, n=80: r[j] = e[j]+e[j+8]+...+e[j+72]; tree combine
    float r[8];
#pragma unroll
    for (int j = 0; j < 8; j++) r[j] = ev[j];
#pragma unroll
    for (int i = 8; i < 80; i += 8)
#pragma unroll
        for (int j = 0; j < 8; j++) r[j] = __fadd_rn(r[j], ev[i + j]);
    float sum = __fadd_rn(
        __fadd_rn(__fadd_rn(r[0], r[1]), __fadd_rn(r[2], r[3])),
        __fadd_rn(__fadd_rn(r[4], r[5]), __fadd_rn(r[6], r[7])));
    // sigmoid(conf) in numpy-f32 semantics
    float s = sigm_np(conf[t]);
    // products s * (e_c / sum), argmax first-index, max value
    float best = -1.0f; int bi = 0;
#pragma unroll
    for (int c = 0; c < 80; c++) {
        float p  = __fdiv_rn(ev[c], sum);
        float sc = __fmul_rn(s, p);
        if (sc > best) { best = sc; bi = c; }
    }
    // key: (f32 score bits desc, index asc) — scores > 0 so bit order = numeric
    keys[t] = ((unsigned long long)__float_as_uint(best) << 32) |
              (unsigned long long)(0xFFFFFFFFu - (unsigned)m);
    labels[t] = bi;
}

// Kernel 2: exact top-K by ranking on unique u64 keys.
__global__ void k_topk(const unsigned long long* __restrict__ keys,
                       const int* __restrict__ labels,
                       int* __restrict__ sel_idx, float* __restrict__ sel_score,
                       int* __restrict__ sel_label) {
    int m = blockIdx.x * blockDim.x + threadIdx.x;   // grid.x = 20, block 256
    int b = blockIdx.y;
    const unsigned long long* kb = keys + (size_t)b * M;
    unsigned long long my = kb[m];
    int rank = 0;
#pragma unroll 4
    for (int j = 0; j < M; j++) {
        rank += (kb[j] > my) ? 1 : 0;   // wave-uniform address -> scalar loads
    }
    if (rank < K) {
        sel_idx[b * K + rank] = m;
        sel_score[b * K + rank] = __uint_as_float((unsigned)(my >> 32));
        sel_label[b * K + rank] = labels[(size_t)b * M + m];
    }
}

// Kernel 3: numpy-f32 decode (mul-then-add, no FMA contraction), clip, and
// class-offset boxes with f32 adds — reference op order throughout.
__global__ void k_decode(const float* __restrict__ reg, const float* __restrict__ anchors,
                         const int* __restrict__ sel_idx, const int* __restrict__ sel_label,
                         float* __restrict__ out, float4* __restrict__ boxes_off) {
    int k = blockIdx.x * blockDim.x + threadIdx.x;   // grid.x = 4, block 256
    int b = blockIdx.y;
    if (k >= K) return;
    int m = sel_idx[b * K + k];
    float4 r = ((const float4*)reg)[(size_t)b * M + m];
    float4 a = ((const float4*)anchors)[m];
    float cx = __fadd_rn(__fmul_rn(sigm_np(r.x), 16.0f), a.x);
    float cy = __fadd_rn(__fmul_rn(sigm_np(r.y), 16.0f), a.y);
    float w  = __fmul_rn(expf_cr(r.z), a.z);
    float h  = __fmul_rn(expf_cr(r.w), a.w);
    float x1 = __fdiv_rn(__fsub_rn(cx, __fmul_rn(0.5f, w)), 512.0f);
    float y1 = __fdiv_rn(__fsub_rn(cy, __fmul_rn(0.5f, h)), 512.0f);
    float x2 = __fdiv_rn(__fadd_rn(cx, __fmul_rn(0.5f, w)), 512.0f);
    float y2 = __fdiv_rn(__fadd_rn(cy, __fmul_rn(0.5f, h)), 512.0f);
    x1 = fminf(fmaxf(x1, 0.0f), 1.0f);
    y1 = fminf(fmaxf(y1, 0.0f), 1.0f);
    x2 = fminf(fmaxf(x2, 0.0f), 1.0f);
    y2 = fminf(fmaxf(y2, 0.0f), 1.0f);
    int lab = sel_label[b * K + k];
    ((float4*)(out + OFF_BOX))[b * K + k] = make_float4(x1, y1, x2, y2);
    out[OFF_LAB + b * K + k] = (float)lab;
    float off = __fmul_rn(2.0f, (float)lab);
    boxes_off[b * K + k] = make_float4(__fadd_rn(x1, off), __fadd_rn(y1, off),
                                       __fadd_rn(x2, off), __fadd_rn(y2, off));
}

// Kernel 4: suppression bitmask, f32 IoU in the reference's exact op order:
// iou = inter / (((a_i + a_j) - inter) + 1e-14)
__global__ void k_mask(const float4* __restrict__ boxes_off,
                       unsigned long long* __restrict__ mask) {
    int b = blockIdx.y;
    int i0 = blockIdx.x * 125;                       // grid.x = 8
    __shared__ float4 sb[K];                         // 16 KB
    __shared__ float  sa[K];                         // 4 KB
    for (int j = threadIdx.x; j < K; j += blockDim.x) {
        float4 bx = boxes_off[b * K + j];
        sb[j] = bx;
        sa[j] = __fmul_rn(__fsub_rn(bx.z, bx.x), __fsub_rn(bx.w, bx.y));
    }
    __syncthreads();
    int i = i0 + threadIdx.x;
    if (threadIdx.x >= 125) return;
    float4 bi = sb[i];
    float ai = sa[i];
    for (int w = 0; w < 16; w++) {
        unsigned long long bits = 0ull;
        int jbase = w * 64;
        for (int jj = 0; jj < 64; jj++) {
            int j = jbase + jj;
            if (j >= K) break;
            float4 bj = sb[j];
            float xx1 = fmaxf(bi.x, bj.x), yy1 = fmaxf(bi.y, bj.y);
            float xx2 = fminf(bi.z, bj.z), yy2 = fminf(bi.w, bj.w);
            float ww = fmaxf(1e-28f, __fsub_rn(xx2, xx1));
            float hh = fmaxf(1e-28f, __fsub_rn(yy2, yy1));
            float inter = __fmul_rn(ww, hh);
            float denom = __fadd_rn(__fsub_rn(__fadd_rn(ai, sa[j]), inter), 1e-14f);
            float iou = __fdiv_rn(inter, denom);
            if (iou > NMS_T) bits |= (1ull << jj);
        }
        mask[((size_t)b * K + i) * 16 + w] = bits;
    }
}

// Kernel 5: sequential NMS scan. One wave per batch; lanes 0..15 own keep words.
__global__ void k_nms(const unsigned long long* __restrict__ mask,
                      unsigned long long* __restrict__ keep) {
    int b = blockIdx.x;
    int lane = threadIdx.x;   // block = 64
    unsigned long long kw = 0ull;
    if (lane < 16) kw = (lane < 15) ? ~0ull : ((1ull << 40) - 1);  // 1000 = 15*64+40
    const unsigned long long* mb = mask + (size_t)b * K * 16;
    for (int i = 0; i < K; i++) {
        int wi = i >> 6, bit = i & 63;
        unsigned long long cur = __shfl(kw, wi, 64);
        if ((cur >> bit) & 1ull) {
            unsigned long long row = (lane < 16) ? mb[(size_t)i * 16 + lane] : 0ull;
            if (lane > wi) {
                kw &= ~row;
            } else if (lane == wi) {
                unsigned long long hi = (bit == 63) ? 0ull : (~0ull << (bit + 1));
                kw &= ~(row & hi);   // only suppress j > i
            }
        }
    }
    if (lane < 16) keep[b * 16 + lane] = kw;
}

// Kernel 6: final score/keep outputs (f32 threshold compare, like reference).
__global__ void k_final(const float* __restrict__ sel_score,
                        const unsigned long long* __restrict__ keep,
                        float* __restrict__ out) {
    int k = blockIdx.x * blockDim.x + threadIdx.x;   // grid.x = 4, block 256
    int b = blockIdx.y;
    if (k >= K) return;
    float s = sel_score[b * K + k];
    bool kp = (((keep[b * 16 + (k >> 6)] >> (k & 63)) & 1ull) != 0ull) && (s >= 0.05f);
    out[OFF_SCORE + b * K + k] = kp ? s : 0.0f;
    out[OFF_KEEP + b * K + k] = kp ? 1.0f : 0.0f;
}

extern "C" void kernel_launch(void* const* d_in, const int* in_sizes, int n_in,
                              void* d_out, int out_size, void* d_ws, size_t ws_size,
                              hipStream_t stream) {
    const float* conf    = (const float*)d_in[0];
    const float* cls     = (const float*)d_in[1];
    const float* reg     = (const float*)d_in[2];
    const float* anchors = (const float*)d_in[3];
    float* out = (float*)d_out;
    char* ws = (char*)d_ws;

    unsigned long long* keys = (unsigned long long*)(ws + WS_KEYS);
    int*    labels   = (int*)(ws + WS_LABELS);
    int*    sel_idx  = (int*)(ws + WS_SELIDX);
    float*  sel_sc   = (float*)(ws + WS_SELSC);
    int*    sel_lab  = (int*)(ws + WS_SELLAB);
    float4* boxes_off = (float4*)(ws + WS_BOXOFF);
    unsigned long long* mask = (unsigned long long*)(ws + WS_MASK);
    unsigned long long* keep = (unsigned long long*)(ws + WS_KEEP);

    k_scores<<<dim3(M / 256, B), 256, 0, stream>>>(conf, cls, keys, labels);
    k_topk  <<<dim3(M / 256, B), 256, 0, stream>>>(keys, labels, sel_idx, sel_sc, sel_lab);
    k_decode<<<dim3(4, B), 256, 0, stream>>>(reg, anchors, sel_idx, sel_lab, out, boxes_off);
    k_mask  <<<dim3(8, B), 128, 0, stream>>>(boxes_off, mask);
    k_nms   <<<32, 64, 0, stream>>>(mask, keep);
    k_final <<<dim3(4, B), 256, 0, stream>>>(sel_sc, keep, out);
}

// Round 5
// 482.147 us; speedup vs baseline: 1.6496x; 1.6496x over previous
//
#include <hip/hip_runtime.h>
#include <cstdint>
#include <math.h>

// Problem constants (from reference)
constexpr int B = 32;
constexpr int M = 5120;          // 32*32*5 anchors
constexpr int C = 80;            // classes
constexpr int K = 1000;          // TOPK
constexpr float NMS_T  = 0.6f;

// d_out layout (flat float32, return order): scores | labels | bboxes | keep
constexpr int OFF_SCORE = 0;
constexpr int OFF_LAB   = B * K;            // 32000
constexpr int OFF_BOX   = 2 * B * K;        // 64000
constexpr int OFF_KEEP  = 2 * B * K + 4 * B * K; // 192000

// workspace layout (bytes)
constexpr size_t WS_KEYS     = 0;                                   // B*M u64
constexpr size_t WS_LABELS   = WS_KEYS   + (size_t)B * M * 8;       // B*M int
constexpr size_t WS_SELIDX   = WS_LABELS + (size_t)B * M * 4;       // B*K int
constexpr size_t WS_SELSC    = WS_SELIDX + (size_t)B * K * 4;       // B*K f32
constexpr size_t WS_SELLAB   = WS_SELSC + (size_t)B * K * 4;        // B*K int
constexpr size_t WS_BOXOFF   = WS_SELLAB + (size_t)B * K * 4;       // B*K*4 f32
constexpr size_t WS_MASK     = WS_BOXOFF + (size_t)B * K * 4 * 4;   // B*K*16 u64

// Correctly-rounded f32 exp: compute in f64 (ocml exp), round once. Verified
// bit-exact vs the harness's np reference (R4 absmax 0.0) — do not change.
__device__ __forceinline__ float expf_cr(float x) {
    return (float)exp((double)x);
}
// numpy-style f32 sigmoid: 1/(1+exp(-x)), every op in f32, no contraction.
__device__ __forceinline__ float sigm_np(float x) {
    float e = expf_cr(-x);
    return __fdiv_rn(1.0f, __fadd_rn(1.0f, e));
}

// Kernel 1: replicate numpy-f32 score_all = sigmoid(conf)*softmax(cls);
// scores = max_c, labels = argmax_c (first max). Softmax denominator uses
// numpy's pairwise-sum order for n=80: 8 accumulators stride-8, tree combine.
__global__ void k_scores(const float* __restrict__ conf, const float* __restrict__ cls,
                         unsigned long long* __restrict__ keys, int* __restrict__ labels) {
    int m = blockIdx.x * blockDim.x + threadIdx.x;   // grid.x = 20, block 256
    int b = blockIdx.y;
    size_t t = (size_t)b * M + m;
    const float4* rowv = (const float4*)(cls + t * C);
    float ev[80];
#pragma unroll
    for (int i = 0; i < 20; i++) {
        float4 v = rowv[i];
        ev[4 * i + 0] = v.x; ev[4 * i + 1] = v.y;
        ev[4 * i + 2] = v.z; ev[4 * i + 3] = v.w;
    }
    float mx = ev[0];
#pragma unroll
    for (int c = 1; c < 80; c++) mx = fmaxf(mx, ev[c]);
#pragma unroll
    for (int c = 0; c < 80; c++) ev[c] = expf_cr(__fsub_rn(ev[c], mx));
    // numpy pairwise sum, n=80: r[j] = e[j]+e[j+8]+...+e[j+72]; tree combine
    float r[8];
#pragma unroll
    for (int j = 0; j < 8; j++) r[j] = ev[j];
#pragma unroll
    for (int i = 8; i < 80; i += 8)
#pragma unroll
        for (int j = 0; j < 8; j++) r[j] = __fadd_rn(r[j], ev[i + j]);
    float sum = __fadd_rn(
        __fadd_rn(__fadd_rn(r[0], r[1]), __fadd_rn(r[2], r[3])),
        __fadd_rn(__fadd_rn(r[4], r[5]), __fadd_rn(r[6], r[7])));
    float s = sigm_np(conf[t]);
    float best = -1.0f; int bi = 0;
#pragma unroll
    for (int c = 0; c < 80; c++) {
        float p  = __fdiv_rn(ev[c], sum);
        float sc = __fmul_rn(s, p);
        if (sc > best) { best = sc; bi = c; }
    }
    keys[t] = ((unsigned long long)__float_as_uint(best) << 32) |
              (unsigned long long)(0xFFFFFFFFu - (unsigned)m);
    labels[t] = bi;
}

// Kernel 2: exact top-K by ranking on unique u64 keys.
__global__ void k_topk(const unsigned long long* __restrict__ keys,
                       const int* __restrict__ labels,
                       int* __restrict__ sel_idx, float* __restrict__ sel_score,
                       int* __restrict__ sel_label) {
    int m = blockIdx.x * blockDim.x + threadIdx.x;   // grid.x = 20, block 256
    int b = blockIdx.y;
    const unsigned long long* kb = keys + (size_t)b * M;
    unsigned long long my = kb[m];
    int rank = 0;
#pragma unroll 4
    for (int j = 0; j < M; j++) {
        rank += (kb[j] > my) ? 1 : 0;   // wave-uniform address -> scalar loads
    }
    if (rank < K) {
        sel_idx[b * K + rank] = m;
        sel_score[b * K + rank] = __uint_as_float((unsigned)(my >> 32));
        sel_label[b * K + rank] = labels[(size_t)b * M + m];
    }
}

// Kernel 3: numpy-f32 decode (mul-then-add, no FMA contraction), clip, and
// class-offset boxes with f32 adds — reference op order throughout.
__global__ void k_decode(const float* __restrict__ reg, const float* __restrict__ anchors,
                         const int* __restrict__ sel_idx, const int* __restrict__ sel_label,
                         float* __restrict__ out, float4* __restrict__ boxes_off) {
    int k = blockIdx.x * blockDim.x + threadIdx.x;   // grid.x = 4, block 256
    int b = blockIdx.y;
    if (k >= K) return;
    int m = sel_idx[b * K + k];
    float4 r = ((const float4*)reg)[(size_t)b * M + m];
    float4 a = ((const float4*)anchors)[m];
    float cx = __fadd_rn(__fmul_rn(sigm_np(r.x), 16.0f), a.x);
    float cy = __fadd_rn(__fmul_rn(sigm_np(r.y), 16.0f), a.y);
    float w  = __fmul_rn(expf_cr(r.z), a.z);
    float h  = __fmul_rn(expf_cr(r.w), a.w);
    float x1 = __fdiv_rn(__fsub_rn(cx, __fmul_rn(0.5f, w)), 512.0f);
    float y1 = __fdiv_rn(__fsub_rn(cy, __fmul_rn(0.5f, h)), 512.0f);
    float x2 = __fdiv_rn(__fadd_rn(cx, __fmul_rn(0.5f, w)), 512.0f);
    float y2 = __fdiv_rn(__fadd_rn(cy, __fmul_rn(0.5f, h)), 512.0f);
    x1 = fminf(fmaxf(x1, 0.0f), 1.0f);
    y1 = fminf(fmaxf(y1, 0.0f), 1.0f);
    x2 = fminf(fmaxf(x2, 0.0f), 1.0f);
    y2 = fminf(fmaxf(y2, 0.0f), 1.0f);
    int lab = sel_label[b * K + k];
    ((float4*)(out + OFF_BOX))[b * K + k] = make_float4(x1, y1, x2, y2);
    out[OFF_LAB + b * K + k] = (float)lab;
    float off = __fmul_rn(2.0f, (float)lab);
    boxes_off[b * K + k] = make_float4(__fadd_rn(x1, off), __fadd_rn(y1, off),
                                       __fadd_rn(x2, off), __fadd_rn(y2, off));
}

// Kernel 4: suppression bitmask, f32 IoU in the reference's exact op order.
__global__ void k_mask(const float4* __restrict__ boxes_off,
                       unsigned long long* __restrict__ mask) {
    int b = blockIdx.y;
    int i0 = blockIdx.x * 125;                       // grid.x = 8
    __shared__ float4 sb[K];                         // 16 KB
    __shared__ float  sa[K];                         // 4 KB
    for (int j = threadIdx.x; j < K; j += blockDim.x) {
        float4 bx = boxes_off[b * K + j];
        sb[j] = bx;
        sa[j] = __fmul_rn(__fsub_rn(bx.z, bx.x), __fsub_rn(bx.w, bx.y));
    }
    __syncthreads();
    int i = i0 + threadIdx.x;
    if (threadIdx.x >= 125) return;
    float4 bi = sb[i];
    float ai = sa[i];
    for (int w = 0; w < 16; w++) {
        unsigned long long bits = 0ull;
        int jbase = w * 64;
        for (int jj = 0; jj < 64; jj++) {
            int j = jbase + jj;
            if (j >= K) break;
            float4 bj = sb[j];
            float xx1 = fmaxf(bi.x, bj.x), yy1 = fmaxf(bi.y, bj.y);
            float xx2 = fminf(bi.z, bj.z), yy2 = fminf(bi.w, bj.w);
            float ww = fmaxf(1e-28f, __fsub_rn(xx2, xx1));
            float hh = fmaxf(1e-28f, __fsub_rn(yy2, yy1));
            float inter = __fmul_rn(ww, hh);
            float denom = __fadd_rn(__fsub_rn(__fadd_rn(ai, sa[j]), inter), 1e-14f);
            float iou = __fdiv_rn(inter, denom);
            if (iou > NMS_T) bits |= (1ull << jj);
        }
        mask[((size_t)b * K + i) * 16 + w] = bits;
    }
}

// Kernel 5: exact NMS via bracketed Jacobi fixed point. Sequential NMS keep is
// the unique fixed point of keep[j] = !any(i<j: keep[i] & mask[i][j]) (well-
// founded by index). f is antitone, so U0=all, L0=none, U<-f(L), L<-f(U)
// brackets the true solution; bits of chain-depth <=k are final after k iters;
// U==L => exact. Thread j holds its i<j-masked row in 16 u64 registers; U/L in
// LDS (wave-uniform broadcast reads); words rebuilt via __ballot (wave w ==
// word w for blockDim 1024). Epilogue = old k_final (folded in).
__global__ void __launch_bounds__(1024)
k_nms(const unsigned long long* __restrict__ mask,
      const float* __restrict__ sel_score,
      float* __restrict__ out) {
    int b = blockIdx.x;
    int j = threadIdx.x;                 // 0..1023
    int w = j >> 6;                      // wave index == keep-word index
    int jb = j & 63;
    __shared__ unsigned long long U[16], L[16];
    __shared__ int flag[2];
    unsigned long long rw[16];
    const unsigned long long* rowp = mask + ((size_t)b * K + j) * 16;
    if (j < K) {
#pragma unroll
        for (int t = 0; t < 16; t++) {
            unsigned long long bm;
            if (t < w)       bm = ~0ull;
            else if (t == w) bm = (jb == 0) ? 0ull : ((1ull << jb) - 1ull);
            else             bm = 0ull;
            rw[t] = bm ? (rowp[t] & bm) : 0ull;   // only i<j can suppress j
        }
    } else {
#pragma unroll
        for (int t = 0; t < 16; t++) rw[t] = 0ull;
    }
    if (j < 16) { U[j] = (j < 15) ? ~0ull : ((1ull << 40) - 1); L[j] = 0ull; }
    if (j == 0) { flag[0] = 0; flag[1] = 0; }
    __syncthreads();
    for (int k = 0; k < 1025; k++) {
        unsigned long long supU = 0ull, supL = 0ull;
#pragma unroll
        for (int t = 0; t < 16; t++) {
            unsigned long long Ut = U[t], Lt = L[t];   // broadcast (same addr)
            supU |= Lt & rw[t];   // new U = f(L)
            supL |= Ut & rw[t];   // new L = f(U)
        }
        bool nu = (j < K) && (supU == 0ull);
        bool nl = (j < K) && (supL == 0ull);
        __syncthreads();                     // all reads of old U/L done
        unsigned long long bu = __ballot(nu);
        unsigned long long bl = __ballot(nl);
        if (jb == 0) {
            U[w] = bu; L[w] = bl;
            if (bu != bl) flag[k & 1] = 1;
        }
        if (j == 0) flag[(k + 1) & 1] = 0;   // pre-clear next slot (unused now)
        __syncthreads();
        if (flag[k & 1] == 0) break;         // uniform exit; U==L == exact keep
    }
    if (j < K) {
        bool kp = ((U[w] >> jb) & 1ull) != 0ull;
        float s = sel_score[b * K + j];
        kp = kp && (s >= 0.05f);
        out[OFF_SCORE + b * K + j] = kp ? s : 0.0f;
        out[OFF_KEEP + b * K + j]  = kp ? 1.0f : 0.0f;
    }
}

extern "C" void kernel_launch(void* const* d_in, const int* in_sizes, int n_in,
                              void* d_out, int out_size, void* d_ws, size_t ws_size,
                              hipStream_t stream) {
    const float* conf    = (const float*)d_in[0];
    const float* cls     = (const float*)d_in[1];
    const float* reg     = (const float*)d_in[2];
    const float* anchors = (const float*)d_in[3];
    float* out = (float*)d_out;
    char* ws = (char*)d_ws;

    unsigned long long* keys = (unsigned long long*)(ws + WS_KEYS);
    int*    labels   = (int*)(ws + WS_LABELS);
    int*    sel_idx  = (int*)(ws + WS_SELIDX);
    float*  sel_sc   = (float*)(ws + WS_SELSC);
    int*    sel_lab  = (int*)(ws + WS_SELLAB);
    float4* boxes_off = (float4*)(ws + WS_BOXOFF);
    unsigned long long* mask = (unsigned long long*)(ws + WS_MASK);

    k_scores<<<dim3(M / 256, B), 256, 0, stream>>>(conf, cls, keys, labels);
    k_topk  <<<dim3(M / 256, B), 256, 0, stream>>>(keys, labels, sel_idx, sel_sc, sel_lab);
    k_decode<<<dim3(4, B), 256, 0, stream>>>(reg, anchors, sel_idx, sel_lab, out, boxes_off);
    k_mask  <<<dim3(8, B), 128, 0, stream>>>(boxes_off, mask);
    k_nms   <<<32, 1024, 0, stream>>>(mask, sel_sc, out);
}

// Round 6
// 286.881 us; speedup vs baseline: 2.7723x; 1.6806x over previous
//
#include <hip/hip_runtime.h>
#include <cstdint>
#include <math.h>

// Problem constants (from reference)
constexpr int B = 32;
constexpr int M = 5120;          // 32*32*5 anchors
constexpr int C = 80;            // classes
constexpr int K = 1000;          // TOPK
constexpr float NMS_T  = 0.6f;

// d_out layout (flat float32, return order): scores | labels | bboxes | keep
constexpr int OFF_SCORE = 0;
constexpr int OFF_LAB   = B * K;            // 32000
constexpr int OFF_BOX   = 2 * B * K;        // 64000
constexpr int OFF_KEEP  = 2 * B * K + 4 * B * K; // 192000

// workspace layout (bytes)
constexpr size_t WS_KEYS     = 0;                                   // B*M u64
constexpr size_t WS_LABELS   = WS_KEYS   + (size_t)B * M * 8;       // B*M int
constexpr size_t WS_SELIDX   = WS_LABELS + (size_t)B * M * 4;       // B*K int
constexpr size_t WS_SELSC    = WS_SELIDX + (size_t)B * K * 4;       // B*K f32
constexpr size_t WS_SELLAB   = WS_SELSC + (size_t)B * K * 4;        // B*K int
constexpr size_t WS_BOXOFF   = WS_SELLAB + (size_t)B * K * 4;       // B*K*4 f32
constexpr size_t WS_MASK     = WS_BOXOFF + (size_t)B * K * 4 * 4;   // B*K*16 u64

// Correctly-rounded f32 exp: compute in f64 (ocml exp), round once. Verified
// bit-exact vs the harness's np reference (R4 absmax 0.0) — do not change.
__device__ __forceinline__ float expf_cr(float x) {
    return (float)exp((double)x);
}
// numpy-style f32 sigmoid: 1/(1+exp(-x)), every op in f32, no contraction.
__device__ __forceinline__ float sigm_np(float x) {
    float e = expf_cr(-x);
    return __fdiv_rn(1.0f, __fadd_rn(1.0f, e));
}

// Kernel 1: replicate numpy-f32 score_all = sigmoid(conf)*softmax(cls);
// scores = max_c, labels = argmax_c (first max). Softmax denominator uses
// numpy's pairwise-sum order for n=80: 8 accumulators stride-8, tree combine.
__global__ void k_scores(const float* __restrict__ conf, const float* __restrict__ cls,
                         unsigned long long* __restrict__ keys, int* __restrict__ labels) {
    int m = blockIdx.x * blockDim.x + threadIdx.x;   // grid.x = 20, block 256
    int b = blockIdx.y;
    size_t t = (size_t)b * M + m;
    const float4* rowv = (const float4*)(cls + t * C);
    float ev[80];
#pragma unroll
    for (int i = 0; i < 20; i++) {
        float4 v = rowv[i];
        ev[4 * i + 0] = v.x; ev[4 * i + 1] = v.y;
        ev[4 * i + 2] = v.z; ev[4 * i + 3] = v.w;
    }
    float mx = ev[0];
#pragma unroll
    for (int c = 1; c < 80; c++) mx = fmaxf(mx, ev[c]);
#pragma unroll
    for (int c = 0; c < 80; c++) ev[c] = expf_cr(__fsub_rn(ev[c], mx));
    // numpy pairwise sum, n=80: r[j] = e[j]+e[j+8]+...+e[j+72]; tree combine
    float r[8];
#pragma unroll
    for (int j = 0; j < 8; j++) r[j] = ev[j];
#pragma unroll
    for (int i = 8; i < 80; i += 8)
#pragma unroll
        for (int j = 0; j < 8; j++) r[j] = __fadd_rn(r[j], ev[i + j]);
    float sum = __fadd_rn(
        __fadd_rn(__fadd_rn(r[0], r[1]), __fadd_rn(r[2], r[3])),
        __fadd_rn(__fadd_rn(r[4], r[5]), __fadd_rn(r[6], r[7])));
    float s = sigm_np(conf[t]);
    float best = -1.0f; int bi = 0;
#pragma unroll
    for (int c = 0; c < 80; c++) {
        float p  = __fdiv_rn(ev[c], sum);
        float sc = __fmul_rn(s, p);
        if (sc > best) { best = sc; bi = c; }
    }
    keys[t] = ((unsigned long long)__float_as_uint(best) << 32) |
              (unsigned long long)(0xFFFFFFFFu - (unsigned)m);
    labels[t] = bi;
}

// Kernel 2: exact top-K via histogram-select + bitonic sort, one block/batch.
// bin = key>>51 (top 13 bits of f32 score bits; max 2032 since score<1).
// Bins are a monotone prefix of the key, so all top-K keys live in bins >=
// threshold bin T (largest T with suffix-count >= K). Candidates (expected
// ~K+300) are compacted to LDS, padded with 0 (< any real key) and bitonic-
// sorted descending on the full u64 key -> ranks 0..K-1 directly. Overflow
// (>2048 candidates) falls back in-kernel to the exact O(M^2) ranking.
__global__ void __launch_bounds__(1024)
k_topk(const unsigned long long* __restrict__ keys,
       const int* __restrict__ labels,
       int* __restrict__ sel_idx, float* __restrict__ sel_score,
       int* __restrict__ sel_label) {
    int b = blockIdx.x;                  // grid = 32
    int tid = threadIdx.x;               // block = 1024
    const unsigned long long* kb = keys + (size_t)b * M;

    __shared__ unsigned int hist[2048];
    __shared__ unsigned int sufA[2048];
    __shared__ unsigned int sufB[2048];
    __shared__ unsigned long long cand[2048];   // 16 KB
    __shared__ int scnt, thrBin, ovf;

    for (int i = tid; i < 2048; i += 1024) hist[i] = 0;
    if (tid == 0) { scnt = 0; ovf = 0; }
    __syncthreads();

    unsigned long long k5[5];
#pragma unroll
    for (int i = 0; i < 5; i++) {
        k5[i] = kb[tid + i * 1024];              // coalesced
        atomicAdd(&hist[(unsigned)(k5[i] >> 51)], 1u);
    }
    __syncthreads();
    // Hillis-Steele suffix scan over 2048 bins (11 steps, ping-pong)
    for (int i = tid; i < 2048; i += 1024) sufA[i] = hist[i];
    __syncthreads();
    unsigned int* src = sufA; unsigned int* dst = sufB;
    for (int d = 1; d < 2048; d <<= 1) {
        for (int i = tid; i < 2048; i += 1024) {
            unsigned int v = src[i];
            if (i + d < 2048) v += src[i + d];
            dst[i] = v;
        }
        __syncthreads();
        unsigned int* tmp = src; src = dst; dst = tmp;
    }
    // threshold bin: unique crossing point of the non-increasing suffix counts
    for (int i = tid; i < 2048; i += 1024) {
        unsigned int s = src[i];
        unsigned int sn = (i + 1 < 2048) ? src[i + 1] : 0u;
        if (s >= (unsigned)K && sn < (unsigned)K) thrBin = i;
    }
    __syncthreads();
    int T = thrBin;
#pragma unroll
    for (int i = 0; i < 5; i++) {
        if ((int)(k5[i] >> 51) >= T) {
            int pos = atomicAdd(&scnt, 1);
            if (pos < 2048) cand[pos] = k5[i]; else ovf = 1;
        }
    }
    __syncthreads();
    if (!ovf) {
        int S = scnt;
        for (int i = tid; i < 2048; i += 1024)
            if (i >= S) cand[i] = 0ull;          // pad: sorts below real keys
        __syncthreads();
        // bitonic sort, 2048 elems descending, 1 pair/thread/stage (66 stages)
        for (int ksz = 2; ksz <= 2048; ksz <<= 1) {
            for (int jsz = ksz >> 1; jsz > 0; jsz >>= 1) {
                int i = 2 * tid - (tid & (jsz - 1));
                unsigned long long a = cand[i], c = cand[i + jsz];
                bool desc = ((i & ksz) == 0);
                if ((a < c) == desc) { cand[i] = c; cand[i + jsz] = a; }
                __syncthreads();
            }
        }
        if (tid < K) {
            unsigned long long key = cand[tid];
            unsigned int mm = 0xFFFFFFFFu - (unsigned)(key & 0xFFFFFFFFu);
            sel_idx[b * K + tid] = (int)mm;
            sel_score[b * K + tid] = __uint_as_float((unsigned)(key >> 32));
            sel_label[b * K + tid] = labels[(size_t)b * M + mm];
        }
    } else {
        // exact fallback (never expected for this data): O(M) rank per key
#pragma unroll
        for (int i = 0; i < 5; i++) {
            unsigned long long my = k5[i];
            int rank = 0;
            for (int j = 0; j < M; j++) rank += (kb[j] > my) ? 1 : 0;
            if (rank < K) {
                int mm = tid + i * 1024;
                sel_idx[b * K + rank] = mm;
                sel_score[b * K + rank] = __uint_as_float((unsigned)(my >> 32));
                sel_label[b * K + rank] = labels[(size_t)b * M + mm];
            }
        }
    }
}

// Kernel 3: numpy-f32 decode (mul-then-add, no FMA contraction), clip, and
// class-offset boxes with f32 adds — reference op order throughout.
__global__ void k_decode(const float* __restrict__ reg, const float* __restrict__ anchors,
                         const int* __restrict__ sel_idx, const int* __restrict__ sel_label,
                         float* __restrict__ out, float4* __restrict__ boxes_off) {
    int k = blockIdx.x * blockDim.x + threadIdx.x;   // grid.x = 4, block 256
    int b = blockIdx.y;
    if (k >= K) return;
    int m = sel_idx[b * K + k];
    float4 r = ((const float4*)reg)[(size_t)b * M + m];
    float4 a = ((const float4*)anchors)[m];
    float cx = __fadd_rn(__fmul_rn(sigm_np(r.x), 16.0f), a.x);
    float cy = __fadd_rn(__fmul_rn(sigm_np(r.y), 16.0f), a.y);
    float w  = __fmul_rn(expf_cr(r.z), a.z);
    float h  = __fmul_rn(expf_cr(r.w), a.w);
    float x1 = __fdiv_rn(__fsub_rn(cx, __fmul_rn(0.5f, w)), 512.0f);
    float y1 = __fdiv_rn(__fsub_rn(cy, __fmul_rn(0.5f, h)), 512.0f);
    float x2 = __fdiv_rn(__fadd_rn(cx, __fmul_rn(0.5f, w)), 512.0f);
    float y2 = __fdiv_rn(__fadd_rn(cy, __fmul_rn(0.5f, h)), 512.0f);
    x1 = fminf(fmaxf(x1, 0.0f), 1.0f);
    y1 = fminf(fmaxf(y1, 0.0f), 1.0f);
    x2 = fminf(fmaxf(x2, 0.0f), 1.0f);
    y2 = fminf(fmaxf(y2, 0.0f), 1.0f);
    int lab = sel_label[b * K + k];
    ((float4*)(out + OFF_BOX))[b * K + k] = make_float4(x1, y1, x2, y2);
    out[OFF_LAB + b * K + k] = (float)lab;
    float off = __fmul_rn(2.0f, (float)lab);
    boxes_off[b * K + k] = make_float4(__fadd_rn(x1, off), __fadd_rn(y1, off),
                                       __fadd_rn(x2, off), __fadd_rn(y2, off));
}

// Kernel 4: suppression bitmask, f32 IoU in the reference's exact op order.
__global__ void k_mask(const float4* __restrict__ boxes_off,
                       unsigned long long* __restrict__ mask) {
    int b = blockIdx.y;
    int i0 = blockIdx.x * 125;                       // grid.x = 8
    __shared__ float4 sb[K];                         // 16 KB
    __shared__ float  sa[K];                         // 4 KB
    for (int j = threadIdx.x; j < K; j += blockDim.x) {
        float4 bx = boxes_off[b * K + j];
        sb[j] = bx;
        sa[j] = __fmul_rn(__fsub_rn(bx.z, bx.x), __fsub_rn(bx.w, bx.y));
    }
    __syncthreads();
    int i = i0 + threadIdx.x;
    if (threadIdx.x >= 125) return;
    float4 bi = sb[i];
    float ai = sa[i];
    for (int w = 0; w < 16; w++) {
        unsigned long long bits = 0ull;
        int jbase = w * 64;
        for (int jj = 0; jj < 64; jj++) {
            int j = jbase + jj;
            if (j >= K) break;
            float4 bj = sb[j];
            float xx1 = fmaxf(bi.x, bj.x), yy1 = fmaxf(bi.y, bj.y);
            float xx2 = fminf(bi.z, bj.z), yy2 = fminf(bi.w, bj.w);
            float ww = fmaxf(1e-28f, __fsub_rn(xx2, xx1));
            float hh = fmaxf(1e-28f, __fsub_rn(yy2, yy1));
            float inter = __fmul_rn(ww, hh);
            float denom = __fadd_rn(__fsub_rn(__fadd_rn(ai, sa[j]), inter), 1e-14f);
            float iou = __fdiv_rn(inter, denom);
            if (iou > NMS_T) bits |= (1ull << jj);
        }
        mask[((size_t)b * K + i) * 16 + w] = bits;
    }
}

// Kernel 5: exact NMS via bracketed Jacobi fixed point (see R5 notes).
__global__ void __launch_bounds__(1024)
k_nms(const unsigned long long* __restrict__ mask,
      const float* __restrict__ sel_score,
      float* __restrict__ out) {
    int b = blockIdx.x;
    int j = threadIdx.x;                 // 0..1023
    int w = j >> 6;                      // wave index == keep-word index
    int jb = j & 63;
    __shared__ unsigned long long U[16], L[16];
    __shared__ int flag[2];
    unsigned long long rw[16];
    const unsigned long long* rowp = mask + ((size_t)b * K + j) * 16;
    if (j < K) {
#pragma unroll
        for (int t = 0; t < 16; t++) {
            unsigned long long bm;
            if (t < w)       bm = ~0ull;
            else if (t == w) bm = (jb == 0) ? 0ull : ((1ull << jb) - 1ull);
            else             bm = 0ull;
            rw[t] = bm ? (rowp[t] & bm) : 0ull;   // only i<j can suppress j
        }
    } else {
#pragma unroll
        for (int t = 0; t < 16; t++) rw[t] = 0ull;
    }
    if (j < 16) { U[j] = (j < 15) ? ~0ull : ((1ull << 40) - 1); L[j] = 0ull; }
    if (j == 0) { flag[0] = 0; flag[1] = 0; }
    __syncthreads();
    for (int k = 0; k < 1025; k++) {
        unsigned long long supU = 0ull, supL = 0ull;
#pragma unroll
        for (int t = 0; t < 16; t++) {
            unsigned long long Ut = U[t], Lt = L[t];   // broadcast (same addr)
            supU |= Lt & rw[t];   // new U = f(L)
            supL |= Ut & rw[t];   // new L = f(U)
        }
        bool nu = (j < K) && (supU == 0ull);
        bool nl = (j < K) && (supL == 0ull);
        __syncthreads();                     // all reads of old U/L done
        unsigned long long bu = __ballot(nu);
        unsigned long long bl = __ballot(nl);
        if (jb == 0) {
            U[w] = bu; L[w] = bl;
            if (bu != bl) flag[k & 1] = 1;
        }
        if (j == 0) flag[(k + 1) & 1] = 0;
        __syncthreads();
        if (flag[k & 1] == 0) break;         // uniform exit; U==L == exact keep
    }
    if (j < K) {
        bool kp = ((U[w] >> jb) & 1ull) != 0ull;
        float s = sel_score[b * K + j];
        kp = kp && (s >= 0.05f);
        out[OFF_SCORE + b * K + j] = kp ? s : 0.0f;
        out[OFF_KEEP + b * K + j]  = kp ? 1.0f : 0.0f;
    }
}

extern "C" void kernel_launch(void* const* d_in, const int* in_sizes, int n_in,
                              void* d_out, int out_size, void* d_ws, size_t ws_size,
                              hipStream_t stream) {
    const float* conf    = (const float*)d_in[0];
    const float* cls     = (const float*)d_in[1];
    const float* reg     = (const float*)d_in[2];
    const float* anchors = (const float*)d_in[3];
    float* out = (float*)d_out;
    char* ws = (char*)d_ws;

    unsigned long long* keys = (unsigned long long*)(ws + WS_KEYS);
    int*    labels   = (int*)(ws + WS_LABELS);
    int*    sel_idx  = (int*)(ws + WS_SELIDX);
    float*  sel_sc   = (float*)(ws + WS_SELSC);
    int*    sel_lab  = (int*)(ws + WS_SELLAB);
    float4* boxes_off = (float4*)(ws + WS_BOXOFF);
    unsigned long long* mask = (unsigned long long*)(ws + WS_MASK);

    k_scores<<<dim3(M / 256, B), 256, 0, stream>>>(conf, cls, keys, labels);
    k_topk  <<<B, 1024, 0, stream>>>(keys, labels, sel_idx, sel_sc, sel_lab);
    k_decode<<<dim3(4, B), 256, 0, stream>>>(reg, anchors, sel_idx, sel_lab, out, boxes_off);
    k_mask  <<<dim3(8, B), 128, 0, stream>>>(boxes_off, mask);
    k_nms   <<<32, 1024, 0, stream>>>(mask, sel_sc, out);
}

// Round 7
// 165.633 us; speedup vs baseline: 4.8017x; 1.7320x over previous
//
#include <hip/hip_runtime.h>
#include <cstdint>
#include <math.h>

// Problem constants (from reference)
constexpr int B = 32;
constexpr int M = 5120;          // 32*32*5 anchors
constexpr int C = 80;            // classes
constexpr int K = 1000;          // TOPK
constexpr float NMS_T  = 0.6f;

// d_out layout (flat float32, return order): scores | labels | bboxes | keep
constexpr int OFF_SCORE = 0;
constexpr int OFF_LAB   = B * K;            // 32000
constexpr int OFF_BOX   = 2 * B * K;        // 64000
constexpr int OFF_KEEP  = 2 * B * K + 4 * B * K; // 192000

// workspace layout (bytes)
constexpr size_t WS_KEYS     = 0;                                   // B*M u64
constexpr size_t WS_LABELS   = WS_KEYS   + (size_t)B * M * 8;       // B*M int
constexpr size_t WS_SELIDX   = WS_LABELS + (size_t)B * M * 4;       // B*K int
constexpr size_t WS_SELSC    = WS_SELIDX + (size_t)B * K * 4;       // B*K f32
constexpr size_t WS_SELLAB   = WS_SELSC + (size_t)B * K * 4;        // B*K int
constexpr size_t WS_BOXOFF   = WS_SELLAB + (size_t)B * K * 4;       // B*K*4 f32
constexpr size_t WS_MASK     = WS_BOXOFF + (size_t)B * K * 4 * 4;   // B*K*16 u64

// Correctly-rounded f32 exp: compute in f64 (ocml exp), round once. Verified
// bit-exact vs the harness's np reference (R4 absmax 0.0) — do not change.
__device__ __forceinline__ float expf_cr(float x) {
    return (float)exp((double)x);
}
// numpy-style f32 sigmoid: 1/(1+exp(-x)), every op in f32, no contraction.
__device__ __forceinline__ float sigm_np(float x) {
    float e = expf_cr(-x);
    return __fdiv_rn(1.0f, __fadd_rn(1.0f, e));
}

// Kernel 1: replicate numpy-f32 score_all = sigmoid(conf)*softmax(cls);
// scores = max_c, labels = argmax_c (first max). Softmax denominator uses
// numpy's pairwise-sum order for n=80: 8 accumulators stride-8, tree combine.
__global__ void k_scores(const float* __restrict__ conf, const float* __restrict__ cls,
                         unsigned long long* __restrict__ keys, int* __restrict__ labels) {
    int m = blockIdx.x * blockDim.x + threadIdx.x;   // grid.x = 20, block 256
    int b = blockIdx.y;
    size_t t = (size_t)b * M + m;
    const float4* rowv = (const float4*)(cls + t * C);
    float ev[80];
#pragma unroll
    for (int i = 0; i < 20; i++) {
        float4 v = rowv[i];
        ev[4 * i + 0] = v.x; ev[4 * i + 1] = v.y;
        ev[4 * i + 2] = v.z; ev[4 * i + 3] = v.w;
    }
    float mx = ev[0];
#pragma unroll
    for (int c = 1; c < 80; c++) mx = fmaxf(mx, ev[c]);
#pragma unroll
    for (int c = 0; c < 80; c++) ev[c] = expf_cr(__fsub_rn(ev[c], mx));
    // numpy pairwise sum, n=80: r[j] = e[j]+e[j+8]+...+e[j+72]; tree combine
    float r[8];
#pragma unroll
    for (int j = 0; j < 8; j++) r[j] = ev[j];
#pragma unroll
    for (int i = 8; i < 80; i += 8)
#pragma unroll
        for (int j = 0; j < 8; j++) r[j] = __fadd_rn(r[j], ev[i + j]);
    float sum = __fadd_rn(
        __fadd_rn(__fadd_rn(r[0], r[1]), __fadd_rn(r[2], r[3])),
        __fadd_rn(__fadd_rn(r[4], r[5]), __fadd_rn(r[6], r[7])));
    float s = sigm_np(conf[t]);
    float best = -1.0f; int bi = 0;
#pragma unroll
    for (int c = 0; c < 80; c++) {
        float p  = __fdiv_rn(ev[c], sum);
        float sc = __fmul_rn(s, p);
        if (sc > best) { best = sc; bi = c; }
    }
    keys[t] = ((unsigned long long)__float_as_uint(best) << 32) |
              (unsigned long long)(0xFFFFFFFFu - (unsigned)m);
    labels[t] = bi;
}

// Kernel 2: exact top-K via histogram-select + bitonic sort, one block/batch.
// (see R6 notes — bin = key>>51, suffix scan, compact, 2048-elem bitonic sort;
// exact O(M^2) fallback if candidates overflow.)
__global__ void __launch_bounds__(1024)
k_topk(const unsigned long long* __restrict__ keys,
       const int* __restrict__ labels,
       int* __restrict__ sel_idx, float* __restrict__ sel_score,
       int* __restrict__ sel_label) {
    int b = blockIdx.x;                  // grid = 32
    int tid = threadIdx.x;               // block = 1024
    const unsigned long long* kb = keys + (size_t)b * M;

    __shared__ unsigned int hist[2048];
    __shared__ unsigned int sufA[2048];
    __shared__ unsigned int sufB[2048];
    __shared__ unsigned long long cand[2048];   // 16 KB
    __shared__ int scnt, thrBin, ovf;

    for (int i = tid; i < 2048; i += 1024) hist[i] = 0;
    if (tid == 0) { scnt = 0; ovf = 0; }
    __syncthreads();

    unsigned long long k5[5];
#pragma unroll
    for (int i = 0; i < 5; i++) {
        k5[i] = kb[tid + i * 1024];              // coalesced
        atomicAdd(&hist[(unsigned)(k5[i] >> 51)], 1u);
    }
    __syncthreads();
    // Hillis-Steele suffix scan over 2048 bins (11 steps, ping-pong)
    for (int i = tid; i < 2048; i += 1024) sufA[i] = hist[i];
    __syncthreads();
    unsigned int* src = sufA; unsigned int* dst = sufB;
    for (int d = 1; d < 2048; d <<= 1) {
        for (int i = tid; i < 2048; i += 1024) {
            unsigned int v = src[i];
            if (i + d < 2048) v += src[i + d];
            dst[i] = v;
        }
        __syncthreads();
        unsigned int* tmp = src; src = dst; dst = tmp;
    }
    // threshold bin: unique crossing point of the non-increasing suffix counts
    for (int i = tid; i < 2048; i += 1024) {
        unsigned int s = src[i];
        unsigned int sn = (i + 1 < 2048) ? src[i + 1] : 0u;
        if (s >= (unsigned)K && sn < (unsigned)K) thrBin = i;
    }
    __syncthreads();
    int T = thrBin;
#pragma unroll
    for (int i = 0; i < 5; i++) {
        if ((int)(k5[i] >> 51) >= T) {
            int pos = atomicAdd(&scnt, 1);
            if (pos < 2048) cand[pos] = k5[i]; else ovf = 1;
        }
    }
    __syncthreads();
    if (!ovf) {
        int S = scnt;
        for (int i = tid; i < 2048; i += 1024)
            if (i >= S) cand[i] = 0ull;          // pad: sorts below real keys
        __syncthreads();
        // bitonic sort, 2048 elems descending, 1 pair/thread/stage (66 stages)
        for (int ksz = 2; ksz <= 2048; ksz <<= 1) {
            for (int jsz = ksz >> 1; jsz > 0; jsz >>= 1) {
                int i = 2 * tid - (tid & (jsz - 1));
                unsigned long long a = cand[i], c = cand[i + jsz];
                bool desc = ((i & ksz) == 0);
                if ((a < c) == desc) { cand[i] = c; cand[i + jsz] = a; }
                __syncthreads();
            }
        }
        if (tid < K) {
            unsigned long long key = cand[tid];
            unsigned int mm = 0xFFFFFFFFu - (unsigned)(key & 0xFFFFFFFFu);
            sel_idx[b * K + tid] = (int)mm;
            sel_score[b * K + tid] = __uint_as_float((unsigned)(key >> 32));
            sel_label[b * K + tid] = labels[(size_t)b * M + mm];
        }
    } else {
        // exact fallback (never expected for this data): O(M) rank per key
#pragma unroll
        for (int i = 0; i < 5; i++) {
            unsigned long long my = k5[i];
            int rank = 0;
            for (int j = 0; j < M; j++) rank += (kb[j] > my) ? 1 : 0;
            if (rank < K) {
                int mm = tid + i * 1024;
                sel_idx[b * K + rank] = mm;
                sel_score[b * K + rank] = __uint_as_float((unsigned)(my >> 32));
                sel_label[b * K + rank] = labels[(size_t)b * M + mm];
            }
        }
    }
}

// Kernel 3: numpy-f32 decode (mul-then-add, no FMA contraction), clip, and
// class-offset boxes with f32 adds — reference op order throughout.
__global__ void k_decode(const float* __restrict__ reg, const float* __restrict__ anchors,
                         const int* __restrict__ sel_idx, const int* __restrict__ sel_label,
                         float* __restrict__ out, float4* __restrict__ boxes_off) {
    int k = blockIdx.x * blockDim.x + threadIdx.x;   // grid.x = 4, block 256
    int b = blockIdx.y;
    if (k >= K) return;
    int m = sel_idx[b * K + k];
    float4 r = ((const float4*)reg)[(size_t)b * M + m];
    float4 a = ((const float4*)anchors)[m];
    float cx = __fadd_rn(__fmul_rn(sigm_np(r.x), 16.0f), a.x);
    float cy = __fadd_rn(__fmul_rn(sigm_np(r.y), 16.0f), a.y);
    float w  = __fmul_rn(expf_cr(r.z), a.z);
    float h  = __fmul_rn(expf_cr(r.w), a.w);
    float x1 = __fdiv_rn(__fsub_rn(cx, __fmul_rn(0.5f, w)), 512.0f);
    float y1 = __fdiv_rn(__fsub_rn(cy, __fmul_rn(0.5f, h)), 512.0f);
    float x2 = __fdiv_rn(__fadd_rn(cx, __fmul_rn(0.5f, w)), 512.0f);
    float y2 = __fdiv_rn(__fadd_rn(cy, __fmul_rn(0.5f, h)), 512.0f);
    x1 = fminf(fmaxf(x1, 0.0f), 1.0f);
    y1 = fminf(fmaxf(y1, 0.0f), 1.0f);
    x2 = fminf(fmaxf(x2, 0.0f), 1.0f);
    y2 = fminf(fmaxf(y2, 0.0f), 1.0f);
    int lab = sel_label[b * K + k];
    ((float4*)(out + OFF_BOX))[b * K + k] = make_float4(x1, y1, x2, y2);
    out[OFF_LAB + b * K + k] = (float)lab;
    float off = __fmul_rn(2.0f, (float)lab);
    boxes_off[b * K + k] = make_float4(__fadd_rn(x1, off), __fadd_rn(y1, off),
                                       __fadd_rn(x2, off), __fadd_rn(y2, off));
}

// Kernel 4: suppression bitmask, re-tiled for occupancy. Block = 256 threads
// = 64 rows x 4 words; grid = (16 row-tiles, 4 word-groups, 32 batches) =
// 2048 blocks = 8 waves/SIMD (was 0.5). Each thread computes one u64 mask
// word (64 IoUs). Inner LDS reads are wave-uniform broadcasts (wg constant
// per wave). j>=K padded with a sentinel box whose IoU is exactly 0
// (inter underflows to 0, area overflows to +inf -> 0/inf = 0, no NaN).
// IoU math unchanged (f32, reference op order) -> mask bits bit-identical.
__global__ void __launch_bounds__(256)
k_mask(const float4* __restrict__ boxes_off,
       unsigned long long* __restrict__ mask) {
    int b = blockIdx.z;
    int rowTile = blockIdx.x;            // 0..15
    int wgGroup = blockIdx.y;            // 0..3
    int tid = threadIdx.x;               // 0..255
    __shared__ float4 sbj[256];
    __shared__ float  saj[256];
    __shared__ float4 sbi[64];
    __shared__ float  sai[64];
    int j = wgGroup * 256 + tid;
    float4 bx = (j < K) ? boxes_off[b * K + j]
                        : make_float4(3e30f, 3e30f, -3e30f, -3e30f);
    sbj[tid] = bx;
    saj[tid] = __fmul_rn(__fsub_rn(bx.z, bx.x), __fsub_rn(bx.w, bx.y));
    if (tid < 64) {
        int i = rowTile * 64 + tid;
        float4 bv = (i < K) ? boxes_off[b * K + i] : make_float4(0, 0, 0, 0);
        sbi[tid] = bv;
        sai[tid] = __fmul_rn(__fsub_rn(bv.z, bv.x), __fsub_rn(bv.w, bv.y));
    }
    __syncthreads();
    int r  = tid & 63;                   // row within tile (lane)
    int wg = tid >> 6;                   // word within group (wave index)
    int i = rowTile * 64 + r;
    if (i >= K) return;
    float4 bi = sbi[r];
    float ai = sai[r];
    unsigned long long bits = 0ull;
    int base = wg * 64;
#pragma unroll 8
    for (int jj = 0; jj < 64; jj++) {
        float4 bj = sbj[base + jj];      // wave-uniform -> broadcast
        float xx1 = fmaxf(bi.x, bj.x), yy1 = fmaxf(bi.y, bj.y);
        float xx2 = fminf(bi.z, bj.z), yy2 = fminf(bi.w, bj.w);
        float ww = fmaxf(1e-28f, __fsub_rn(xx2, xx1));
        float hh = fmaxf(1e-28f, __fsub_rn(yy2, yy1));
        float inter = __fmul_rn(ww, hh);
        float denom = __fadd_rn(__fsub_rn(__fadd_rn(ai, saj[base + jj]), inter), 1e-14f);
        float iou = __fdiv_rn(inter, denom);
        if (iou > NMS_T) bits |= (1ull << jj);
    }
    mask[((size_t)b * K + i) * 16 + wgGroup * 4 + wg] = bits;
}

// Kernel 5: exact NMS via bracketed Jacobi fixed point (see R5 notes).
__global__ void __launch_bounds__(1024)
k_nms(const unsigned long long* __restrict__ mask,
      const float* __restrict__ sel_score,
      float* __restrict__ out) {
    int b = blockIdx.x;
    int j = threadIdx.x;                 // 0..1023
    int w = j >> 6;                      // wave index == keep-word index
    int jb = j & 63;
    __shared__ unsigned long long U[16], L[16];
    __shared__ int flag[2];
    unsigned long long rw[16];
    const unsigned long long* rowp = mask + ((size_t)b * K + j) * 16;
    if (j < K) {
#pragma unroll
        for (int t = 0; t < 16; t++) {
            unsigned long long bm;
            if (t < w)       bm = ~0ull;
            else if (t == w) bm = (jb == 0) ? 0ull : ((1ull << jb) - 1ull);
            else             bm = 0ull;
            rw[t] = bm ? (rowp[t] & bm) : 0ull;   // only i<j can suppress j
        }
    } else {
#pragma unroll
        for (int t = 0; t < 16; t++) rw[t] = 0ull;
    }
    if (j < 16) { U[j] = (j < 15) ? ~0ull : ((1ull << 40) - 1); L[j] = 0ull; }
    if (j == 0) { flag[0] = 0; flag[1] = 0; }
    __syncthreads();
    for (int k = 0; k < 1025; k++) {
        unsigned long long supU = 0ull, supL = 0ull;
#pragma unroll
        for (int t = 0; t < 16; t++) {
            unsigned long long Ut = U[t], Lt = L[t];   // broadcast (same addr)
            supU |= Lt & rw[t];   // new U = f(L)
            supL |= Ut & rw[t];   // new L = f(U)
        }
        bool nu = (j < K) && (supU == 0ull);
        bool nl = (j < K) && (supL == 0ull);
        __syncthreads();                     // all reads of old U/L done
        unsigned long long bu = __ballot(nu);
        unsigned long long bl = __ballot(nl);
        if (jb == 0) {
            U[w] = bu; L[w] = bl;
            if (bu != bl) flag[k & 1] = 1;
        }
        if (j == 0) flag[(k + 1) & 1] = 0;
        __syncthreads();
        if (flag[k & 1] == 0) break;         // uniform exit; U==L == exact keep
    }
    if (j < K) {
        bool kp = ((U[w] >> jb) & 1ull) != 0ull;
        float s = sel_score[b * K + j];
        kp = kp && (s >= 0.05f);
        out[OFF_SCORE + b * K + j] = kp ? s : 0.0f;
        out[OFF_KEEP + b * K + j]  = kp ? 1.0f : 0.0f;
    }
}

extern "C" void kernel_launch(void* const* d_in, const int* in_sizes, int n_in,
                              void* d_out, int out_size, void* d_ws, size_t ws_size,
                              hipStream_t stream) {
    const float* conf    = (const float*)d_in[0];
    const float* cls     = (const float*)d_in[1];
    const float* reg     = (const float*)d_in[2];
    const float* anchors = (const float*)d_in[3];
    float* out = (float*)d_out;
    char* ws = (char*)d_ws;

    unsigned long long* keys = (unsigned long long*)(ws + WS_KEYS);
    int*    labels   = (int*)(ws + WS_LABELS);
    int*    sel_idx  = (int*)(ws + WS_SELIDX);
    float*  sel_sc   = (float*)(ws + WS_SELSC);
    int*    sel_lab  = (int*)(ws + WS_SELLAB);
    float4* boxes_off = (float4*)(ws + WS_BOXOFF);
    unsigned long long* mask = (unsigned long long*)(ws + WS_MASK);

    k_scores<<<dim3(M / 256, B), 256, 0, stream>>>(conf, cls, keys, labels);
    k_topk  <<<B, 1024, 0, stream>>>(keys, labels, sel_idx, sel_sc, sel_lab);
    k_decode<<<dim3(4, B), 256, 0, stream>>>(reg, anchors, sel_idx, sel_lab, out, boxes_off);
    k_mask  <<<dim3(16, 4, B), 256, 0, stream>>>(boxes_off, mask);
    k_nms   <<<32, 1024, 0, stream>>>(mask, sel_sc, out);
}

// Round 8
// 163.236 us; speedup vs baseline: 4.8723x; 1.0147x over previous
//
#include <hip/hip_runtime.h>
#include <cstdint>
#include <math.h>

// Problem constants (from reference)
constexpr int B = 32;
constexpr int M = 5120;          // 32*32*5 anchors
constexpr int C = 80;            // classes
constexpr int K = 1000;          // TOPK
constexpr float NMS_T  = 0.6f;

// d_out layout (flat float32, return order): scores | labels | bboxes | keep
constexpr int OFF_SCORE = 0;
constexpr int OFF_LAB   = B * K;            // 32000
constexpr int OFF_BOX   = 2 * B * K;        // 64000
constexpr int OFF_KEEP  = 2 * B * K + 4 * B * K; // 192000

// workspace layout (bytes)
constexpr size_t WS_KEYS     = 0;                                   // B*M u64
constexpr size_t WS_LABELS   = WS_KEYS   + (size_t)B * M * 8;       // B*M int
constexpr size_t WS_SELSC    = WS_LABELS + (size_t)B * M * 4;       // B*K f32
constexpr size_t WS_BOXOFF   = WS_SELSC + (size_t)B * K * 4;        // B*K*4 f32
constexpr size_t WS_MASK     = WS_BOXOFF + (size_t)B * K * 4 * 4;   // B*K*16 u64

// Correctly-rounded f32 exp: compute in f64 (ocml exp), round once. Verified
// bit-exact vs the harness's np reference (R4 absmax 0.0) — do not change.
__device__ __forceinline__ float expf_cr(float x) {
    return (float)exp((double)x);
}
// numpy-style f32 sigmoid: 1/(1+exp(-x)), every op in f32, no contraction.
__device__ __forceinline__ float sigm_np(float x) {
    float e = expf_cr(-x);
    return __fdiv_rn(1.0f, __fadd_rn(1.0f, e));
}

// Kernel 1: replicate numpy-f32 score_all = sigmoid(conf)*softmax(cls);
// scores = max_c, labels = argmax_c (first max). Softmax denominator uses
// numpy's pairwise-sum order for n=80: 8 accumulators stride-8, tree combine.
__global__ void k_scores(const float* __restrict__ conf, const float* __restrict__ cls,
                         unsigned long long* __restrict__ keys, int* __restrict__ labels) {
    int m = blockIdx.x * blockDim.x + threadIdx.x;   // grid.x = 20, block 256
    int b = blockIdx.y;
    size_t t = (size_t)b * M + m;
    const float4* rowv = (const float4*)(cls + t * C);
    float ev[80];
#pragma unroll
    for (int i = 0; i < 20; i++) {
        float4 v = rowv[i];
        ev[4 * i + 0] = v.x; ev[4 * i + 1] = v.y;
        ev[4 * i + 2] = v.z; ev[4 * i + 3] = v.w;
    }
    float mx = ev[0];
#pragma unroll
    for (int c = 1; c < 80; c++) mx = fmaxf(mx, ev[c]);
#pragma unroll
    for (int c = 0; c < 80; c++) ev[c] = expf_cr(__fsub_rn(ev[c], mx));
    // numpy pairwise sum, n=80: r[j] = e[j]+e[j+8]+...+e[j+72]; tree combine
    float r[8];
#pragma unroll
    for (int j = 0; j < 8; j++) r[j] = ev[j];
#pragma unroll
    for (int i = 8; i < 80; i += 8)
#pragma unroll
        for (int j = 0; j < 8; j++) r[j] = __fadd_rn(r[j], ev[i + j]);
    float sum = __fadd_rn(
        __fadd_rn(__fadd_rn(r[0], r[1]), __fadd_rn(r[2], r[3])),
        __fadd_rn(__fadd_rn(r[4], r[5]), __fadd_rn(r[6], r[7])));
    float s = sigm_np(conf[t]);
    float best = -1.0f; int bi = 0;
#pragma unroll
    for (int c = 0; c < 80; c++) {
        float p  = __fdiv_rn(ev[c], sum);
        float sc = __fmul_rn(s, p);
        if (sc > best) { best = sc; bi = c; }
    }
    keys[t] = ((unsigned long long)__float_as_uint(best) << 32) |
              (unsigned long long)(0xFFFFFFFFu - (unsigned)m);
    labels[t] = bi;
}

// Decode one selected box (numpy-f32 op order) and write all its outputs.
__device__ __forceinline__ void decode_write(
    int b, int rank, int m, float score, int lab,
    const float* __restrict__ reg, const float* __restrict__ anchors,
    float* __restrict__ out, float4* __restrict__ boxes_off,
    float* __restrict__ sel_score)
{
    float4 r = ((const float4*)reg)[(size_t)b * M + m];
    float4 a = ((const float4*)anchors)[m];
    float cx = __fadd_rn(__fmul_rn(sigm_np(r.x), 16.0f), a.x);
    float cy = __fadd_rn(__fmul_rn(sigm_np(r.y), 16.0f), a.y);
    float w  = __fmul_rn(expf_cr(r.z), a.z);
    float h  = __fmul_rn(expf_cr(r.w), a.w);
    float x1 = __fdiv_rn(__fsub_rn(cx, __fmul_rn(0.5f, w)), 512.0f);
    float y1 = __fdiv_rn(__fsub_rn(cy, __fmul_rn(0.5f, h)), 512.0f);
    float x2 = __fdiv_rn(__fadd_rn(cx, __fmul_rn(0.5f, w)), 512.0f);
    float y2 = __fdiv_rn(__fadd_rn(cy, __fmul_rn(0.5f, h)), 512.0f);
    x1 = fminf(fmaxf(x1, 0.0f), 1.0f);
    y1 = fminf(fmaxf(y1, 0.0f), 1.0f);
    x2 = fminf(fmaxf(x2, 0.0f), 1.0f);
    y2 = fminf(fmaxf(y2, 0.0f), 1.0f);
    ((float4*)(out + OFF_BOX))[b * K + rank] = make_float4(x1, y1, x2, y2);
    out[OFF_LAB + b * K + rank] = (float)lab;
    float off = __fmul_rn(2.0f, (float)lab);
    boxes_off[b * K + rank] = make_float4(__fadd_rn(x1, off), __fadd_rn(y1, off),
                                          __fadd_rn(x2, off), __fadd_rn(y2, off));
    sel_score[b * K + rank] = score;
}

// Kernel 2: exact top-K via histogram-select + bitonic sort, one block/batch,
// with the decode fused into the epilogue. Candidate count S is typically
// ~K+hist[T] (~1005), so we sort 1024 elements (55 stages) when S<=1024 and
// fall back to 2048 (66 stages) otherwise. Exact O(M^2) fallback on overflow.
__global__ void __launch_bounds__(1024)
k_topk(const unsigned long long* __restrict__ keys,
       const int* __restrict__ labels,
       const float* __restrict__ reg, const float* __restrict__ anchors,
       float* __restrict__ out, float4* __restrict__ boxes_off,
       float* __restrict__ sel_score) {
    int b = blockIdx.x;                  // grid = 32
    int tid = threadIdx.x;               // block = 1024
    const unsigned long long* kb = keys + (size_t)b * M;

    __shared__ unsigned int hist[2048];
    __shared__ unsigned int sufA[2048];
    __shared__ unsigned int sufB[2048];
    __shared__ unsigned long long cand[2048];   // 16 KB
    __shared__ int scnt, thrBin, ovf;

    for (int i = tid; i < 2048; i += 1024) hist[i] = 0;
    if (tid == 0) { scnt = 0; ovf = 0; }
    __syncthreads();

    unsigned long long k5[5];
#pragma unroll
    for (int i = 0; i < 5; i++) {
        k5[i] = kb[tid + i * 1024];              // coalesced
        atomicAdd(&hist[(unsigned)(k5[i] >> 51)], 1u);
    }
    __syncthreads();
    // Hillis-Steele suffix scan over 2048 bins (11 steps, ping-pong)
    for (int i = tid; i < 2048; i += 1024) sufA[i] = hist[i];
    __syncthreads();
    unsigned int* src = sufA; unsigned int* dst = sufB;
    for (int d = 1; d < 2048; d <<= 1) {
        for (int i = tid; i < 2048; i += 1024) {
            unsigned int v = src[i];
            if (i + d < 2048) v += src[i + d];
            dst[i] = v;
        }
        __syncthreads();
        unsigned int* tmp = src; src = dst; dst = tmp;
    }
    // threshold bin: unique crossing point of the non-increasing suffix counts
    for (int i = tid; i < 2048; i += 1024) {
        unsigned int s = src[i];
        unsigned int sn = (i + 1 < 2048) ? src[i + 1] : 0u;
        if (s >= (unsigned)K && sn < (unsigned)K) thrBin = i;
    }
    __syncthreads();
    int T = thrBin;
#pragma unroll
    for (int i = 0; i < 5; i++) {
        if ((int)(k5[i] >> 51) >= T) {
            int pos = atomicAdd(&scnt, 1);
            if (pos < 2048) cand[pos] = k5[i]; else ovf = 1;
        }
    }
    __syncthreads();
    if (!ovf) {
        int S = scnt;
        int N = (S <= 1024) ? 1024 : 2048;       // uniform across block
        for (int i = tid; i < 2048; i += 1024)
            if (i >= S) cand[i] = 0ull;          // pad: sorts below real keys
        __syncthreads();
        // bitonic sort, N elems descending (N/2 pairs per stage)
        for (int ksz = 2; ksz <= N; ksz <<= 1) {
            for (int jsz = ksz >> 1; jsz > 0; jsz >>= 1) {
                if (tid < (N >> 1)) {
                    int i = 2 * tid - (tid & (jsz - 1));
                    unsigned long long a = cand[i], c = cand[i + jsz];
                    bool desc = ((i & ksz) == 0);
                    if ((a < c) == desc) { cand[i] = c; cand[i + jsz] = a; }
                }
                __syncthreads();
            }
        }
        if (tid < K) {
            unsigned long long key = cand[tid];
            int mm = (int)(0xFFFFFFFFu - (unsigned)(key & 0xFFFFFFFFu));
            float sc = __uint_as_float((unsigned)(key >> 32));
            int lab = labels[(size_t)b * M + mm];
            decode_write(b, tid, mm, sc, lab, reg, anchors, out, boxes_off, sel_score);
        }
    } else {
        // exact fallback (never expected for this data): O(M) rank per key
#pragma unroll
        for (int i = 0; i < 5; i++) {
            unsigned long long my = k5[i];
            int rank = 0;
            for (int j = 0; j < M; j++) rank += (kb[j] > my) ? 1 : 0;
            if (rank < K) {
                int mm = tid + i * 1024;
                float sc = __uint_as_float((unsigned)(my >> 32));
                int lab = labels[(size_t)b * M + mm];
                decode_write(b, rank, mm, sc, lab, reg, anchors, out, boxes_off, sel_score);
            }
        }
    }
}

// Kernel 3: suppression bitmask, occupancy-tiled + lower-triangle only.
// k_nms consumes word t of row j only when t <= j>>6 (its bm zeroes the rest
// and skips those reads), so word W of row i is needed iff W <= i>>6 ==
// rowTile. Blocks with 4*wgGroup > rowTile exit before staging (uniform);
// waves with W > rowTile exit after the barrier. ~47% of IoU work removed;
// every consumed bit is bit-identical (f32 IoU, reference op order).
__global__ void __launch_bounds__(256)
k_mask(const float4* __restrict__ boxes_off,
       unsigned long long* __restrict__ mask) {
    int b = blockIdx.z;
    int rowTile = blockIdx.x;            // 0..15
    int wgGroup = blockIdx.y;            // 0..3
    if (4 * wgGroup > rowTile) return;   // block-uniform: no needed words
    int tid = threadIdx.x;               // 0..255
    __shared__ float4 sbj[256];
    __shared__ float  saj[256];
    __shared__ float4 sbi[64];
    __shared__ float  sai[64];
    int j = wgGroup * 256 + tid;
    float4 bx = (j < K) ? boxes_off[b * K + j]
                        : make_float4(3e30f, 3e30f, -3e30f, -3e30f);
    sbj[tid] = bx;
    saj[tid] = __fmul_rn(__fsub_rn(bx.z, bx.x), __fsub_rn(bx.w, bx.y));
    if (tid < 64) {
        int i = rowTile * 64 + tid;
        float4 bv = (i < K) ? boxes_off[b * K + i] : make_float4(0, 0, 0, 0);
        sbi[tid] = bv;
        sai[tid] = __fmul_rn(__fsub_rn(bv.z, bv.x), __fsub_rn(bv.w, bv.y));
    }
    __syncthreads();
    int r  = tid & 63;                   // row within tile (lane)
    int wg = tid >> 6;                   // word within group (wave index)
    int W  = wgGroup * 4 + wg;           // global word index (wave-uniform)
    if (W > rowTile) return;             // whole-wave exit, after the barrier
    int i = rowTile * 64 + r;
    if (i >= K) return;
    float4 bi = sbi[r];
    float ai = sai[r];
    unsigned long long bits = 0ull;
    int base = wg * 64;
#pragma unroll 8
    for (int jj = 0; jj < 64; jj++) {
        float4 bj = sbj[base + jj];      // wave-uniform -> broadcast
        float xx1 = fmaxf(bi.x, bj.x), yy1 = fmaxf(bi.y, bj.y);
        float xx2 = fminf(bi.z, bj.z), yy2 = fminf(bi.w, bj.w);
        float ww = fmaxf(1e-28f, __fsub_rn(xx2, xx1));
        float hh = fmaxf(1e-28f, __fsub_rn(yy2, yy1));
        float inter = __fmul_rn(ww, hh);
        float denom = __fadd_rn(__fsub_rn(__fadd_rn(ai, saj[base + jj]), inter), 1e-14f);
        float iou = __fdiv_rn(inter, denom);
        if (iou > NMS_T) bits |= (1ull << jj);
    }
    mask[((size_t)b * K + i) * 16 + W] = bits;
}

// Kernel 4: exact NMS via bracketed Jacobi fixed point (see R5 notes).
// Row load vectorized: 8x ulonglong2 (contiguous 128 B/thread, coalesced),
// then the i<j mask applied in-register. Words W > j>>6 of row j are never
// written by k_mask now; they're read here but ANDed with bm=0 (harmless,
// in-bounds ws memory).
__global__ void __launch_bounds__(1024)
k_nms(const unsigned long long* __restrict__ mask,
      const float* __restrict__ sel_score,
      float* __restrict__ out) {
    int b = blockIdx.x;
    int j = threadIdx.x;                 // 0..1023
    int w = j >> 6;                      // wave index == keep-word index
    int jb = j & 63;
    __shared__ unsigned long long U[16], L[16];
    __shared__ int flag[2];
    unsigned long long rw[16];
    if (j < K) {
        const ulonglong2* rp2 =
            (const ulonglong2*)(mask + ((size_t)b * K + j) * 16);
#pragma unroll
        for (int t = 0; t < 8; t++) {
            ulonglong2 v = rp2[t];
            rw[2 * t] = v.x; rw[2 * t + 1] = v.y;
        }
#pragma unroll
        for (int t = 0; t < 16; t++) {
            unsigned long long bm =
                (t < w) ? ~0ull
                        : ((t == w && jb != 0) ? ((1ull << jb) - 1ull) : 0ull);
            rw[t] &= bm;                 // only i<j can suppress j
        }
    } else {
#pragma unroll
        for (int t = 0; t < 16; t++) rw[t] = 0ull;
    }
    if (j < 16) { U[j] = (j < 15) ? ~0ull : ((1ull << 40) - 1); L[j] = 0ull; }
    if (j == 0) { flag[0] = 0; flag[1] = 0; }
    __syncthreads();
    for (int k = 0; k < 1025; k++) {
        unsigned long long supU = 0ull, supL = 0ull;
#pragma unroll
        for (int t = 0; t < 16; t++) {
            unsigned long long Ut = U[t], Lt = L[t];   // broadcast (same addr)
            supU |= Lt & rw[t];   // new U = f(L)
            supL |= Ut & rw[t];   // new L = f(U)
        }
        bool nu = (j < K) && (supU == 0ull);
        bool nl = (j < K) && (supL == 0ull);
        __syncthreads();                     // all reads of old U/L done
        unsigned long long bu = __ballot(nu);
        unsigned long long bl = __ballot(nl);
        if (jb == 0) {
            U[w] = bu; L[w] = bl;
            if (bu != bl) flag[k & 1] = 1;
        }
        if (j == 0) flag[(k + 1) & 1] = 0;
        __syncthreads();
        if (flag[k & 1] == 0) break;         // uniform exit; U==L == exact keep
    }
    if (j < K) {
        bool kp = ((U[w] >> jb) & 1ull) != 0ull;
        float s = sel_score[b * K + j];
        kp = kp && (s >= 0.05f);
        out[OFF_SCORE + b * K + j] = kp ? s : 0.0f;
        out[OFF_KEEP + b * K + j]  = kp ? 1.0f : 0.0f;
    }
}

extern "C" void kernel_launch(void* const* d_in, const int* in_sizes, int n_in,
                              void* d_out, int out_size, void* d_ws, size_t ws_size,
                              hipStream_t stream) {
    const float* conf    = (const float*)d_in[0];
    const float* cls     = (const float*)d_in[1];
    const float* reg     = (const float*)d_in[2];
    const float* anchors = (const float*)d_in[3];
    float* out = (float*)d_out;
    char* ws = (char*)d_ws;

    unsigned long long* keys = (unsigned long long*)(ws + WS_KEYS);
    int*    labels   = (int*)(ws + WS_LABELS);
    float*  sel_sc   = (float*)(ws + WS_SELSC);
    float4* boxes_off = (float4*)(ws + WS_BOXOFF);
    unsigned long long* mask = (unsigned long long*)(ws + WS_MASK);

    k_scores<<<dim3(M / 256, B), 256, 0, stream>>>(conf, cls, keys, labels);
    k_topk  <<<B, 1024, 0, stream>>>(keys, labels, reg, anchors, out, boxes_off, sel_sc);
    k_mask  <<<dim3(16, 4, B), 256, 0, stream>>>(boxes_off, mask);
    k_nms   <<<32, 1024, 0, stream>>>(mask, sel_sc, out);
}